// Round 3
// baseline (1019.999 us; speedup 1.0000x reference)
//
#include <hip/hip_runtime.h>
#include <math.h>

#define D 256
#define V 10000
#define BB 16
#define NN 22
#define CF 400
#define CR 120
#define CA 48
#define NEGV -1000000000.0f
#define PSTRIDE 12   // max k-chunks per (s,b) is 11 (w=22)
#define KCMAX 7      // max k-slices staged per partial block

// ---------------- root scores: log_softmax(root_mask + root_w + root_b) ----------------
__global__ void k_root(const float* __restrict__ root_w, const float* __restrict__ root_b,
                       const float* __restrict__ root_mask, float* __restrict__ root_scores) {
  __shared__ float red[512];
  int t = threadIdx.x;
  float x = (t < CF) ? (root_mask[t] + root_w[t] + root_b[t]) : -INFINITY;
  red[t] = x; __syncthreads();
  for (int off = 256; off; off >>= 1) { if (t < off) red[t] = fmaxf(red[t], red[t + off]); __syncthreads(); }
  float m = red[0]; __syncthreads();
  red[t] = (t < CF) ? __expf(x - m) : 0.f; __syncthreads();
  for (int off = 256; off; off >>= 1) { if (t < off) red[t] += red[t + off]; __syncthreads(); }
  float z = m + __logf(red[0]);
  if (t < CF) root_scores[t] = x - z;
}

// ---------------- MLP with split-K: 1024 threads = 4 d-quarters x 256 cols, 4 rows/block ----
__global__ __launch_bounds__(1024) void k_mlp(const float* __restrict__ nt_emb, const float* __restrict__ W1,
                      const float* __restrict__ b1, const float* __restrict__ resW,
                      const float* __restrict__ resb, const float* __restrict__ Wo,
                      const float* __restrict__ bo, float* __restrict__ split_scores) {
  __shared__ float xs[4][D];
  __shared__ float hs[4][D];
  __shared__ float ts[4][D];
  __shared__ float part[16][D];   // [ri*4+q][t]
  __shared__ float redg[4][8];
  int tid = threadIdx.x;
  int q = tid >> 8;      // d-quarter
  int t = tid & 255;     // output col
  int f0 = blockIdx.x * 4;
  xs[q][t] = nt_emb[(f0 + q) * D + t];
  __syncthreads();
  int d0 = q * 64;
  // ---- layer 1: hs = xs@W1 + b1 (no relu) ----
  {
    float a0 = 0.f, a1 = 0.f, a2 = 0.f, a3 = 0.f;
    for (int dd = 0; dd < 64; ++dd) {
      float wv = W1[(d0 + dd) * D + t];
      a0 += xs[0][d0 + dd] * wv; a1 += xs[1][d0 + dd] * wv;
      a2 += xs[2][d0 + dd] * wv; a3 += xs[3][d0 + dd] * wv;
    }
    part[0 * 4 + q][t] = a0; part[1 * 4 + q][t] = a1;
    part[2 * 4 + q][t] = a2; part[3 * 4 + q][t] = a3;
  }
  __syncthreads();
  hs[q][t] = part[q * 4 + 0][t] + part[q * 4 + 1][t] + part[q * 4 + 2][t] + part[q * 4 + 3][t] + b1[t];
  __syncthreads();
  for (int i = 0; i < 2; i++) {
    // ts = relu(hs @ resW[i,0] + resb[i,0])
    {
      const float* W = resW + (size_t)(i * 2 + 0) * D * D;
      float a0 = 0.f, a1 = 0.f, a2 = 0.f, a3 = 0.f;
      for (int dd = 0; dd < 64; ++dd) {
        float wv = W[(d0 + dd) * D + t];
        a0 += hs[0][d0 + dd] * wv; a1 += hs[1][d0 + dd] * wv;
        a2 += hs[2][d0 + dd] * wv; a3 += hs[3][d0 + dd] * wv;
      }
      part[0 * 4 + q][t] = a0; part[1 * 4 + q][t] = a1;
      part[2 * 4 + q][t] = a2; part[3 * 4 + q][t] = a3;
    }
    __syncthreads();
    ts[q][t] = fmaxf(part[q * 4 + 0][t] + part[q * 4 + 1][t] + part[q * 4 + 2][t] + part[q * 4 + 3][t]
                     + resb[(i * 2 + 0) * D + t], 0.f);
    __syncthreads();
    // hs += relu(ts @ resW[i,1] + resb[i,1])
    {
      const float* W = resW + (size_t)(i * 2 + 1) * D * D;
      float a0 = 0.f, a1 = 0.f, a2 = 0.f, a3 = 0.f;
      for (int dd = 0; dd < 64; ++dd) {
        float wv = W[(d0 + dd) * D + t];
        a0 += ts[0][d0 + dd] * wv; a1 += ts[1][d0 + dd] * wv;
        a2 += ts[2][d0 + dd] * wv; a3 += ts[3][d0 + dd] * wv;
      }
      part[0 * 4 + q][t] = a0; part[1 * 4 + q][t] = a1;
      part[2 * 4 + q][t] = a2; part[3 * 4 + q][t] = a3;
    }
    __syncthreads();
    hs[q][t] = fmaxf(part[q * 4 + 0][t] + part[q * 4 + 1][t] + part[q * 4 + 2][t] + part[q * 4 + 3][t]
                     + resb[(i * 2 + 1) * D + t], 0.f) + hs[q][t];
    __syncthreads();
  }
  // ---- output: group q reduces row q ----
  float y0 = hs[q][t] * Wo[t * 2 + 0];
  float y1 = hs[q][t] * Wo[t * 2 + 1];
  for (int off = 32; off; off >>= 1) { y0 += __shfl_down(y0, off, 64); y1 += __shfl_down(y1, off, 64); }
  int lane = t & 63, wv = t >> 6;
  if (lane == 0) { redg[q][wv * 2] = y0; redg[q][wv * 2 + 1] = y1; }
  __syncthreads();
  if (t == 0) {
    float s0 = redg[q][0] + redg[q][2] + redg[q][4] + redg[q][6] + bo[0];
    float s1 = redg[q][1] + redg[q][3] + redg[q][5] + redg[q][7] + bo[1];
    float m = fmaxf(s0, s1);
    float z = m + __logf(__expf(s0 - m) + __expf(s1 - m));
    split_scores[(f0 + q) * 2 + 0] = s0 - z;
    split_scores[(f0 + q) * 2 + 1] = s1 - z;
  }
}

// ---------------- egL/egR = exp(rule log-softmax + split0)  (fake_emb is identity) ----------------
__global__ void k_glgr(const float* __restrict__ rule_W, const float* __restrict__ rule_b,
                       const float* __restrict__ split_scores,
                       float* __restrict__ egL, float* __restrict__ egR) {
  __shared__ float red[128];
  int r = blockIdx.x;
  int t = threadIdx.x;
  float x = (t < 96) ? (rule_W[t * CR + r] + rule_b[t]) : -INFINITY;
  red[t] = x; __syncthreads();
  for (int off = 64; off; off >>= 1) { if (t < off) red[t] = fmaxf(red[t], red[t + off]); __syncthreads(); }
  float m = red[0]; __syncthreads();
  red[t] = (t < 96) ? __expf(x - m) : 0.f; __syncthreads();
  for (int off = 64; off; off >>= 1) { if (t < off) red[t] += red[t + off]; __syncthreads(); }
  float z = m + __logf(red[0]);
  float s0 = split_scores[r * 2 + 0];
  if (t < CA) egL[r * CA + t] = __expf((x - z) + s0);
  else if (t < 96) egR[r * CA + (t - CA)] = __expf((x - z) + s0);
}

// ---------------- emission: per-row partial sum of exp(logits), float4 over v, RT=16 ----------------
#define RT 16
__global__ __launch_bounds__(256) void k_emit_partial(const float* __restrict__ nt_emb,
                               const float* __restrict__ emit_W,
                               const float* __restrict__ emit_b, float* __restrict__ partial) {
  __shared__ float xs[RT][D];
  __shared__ float ldsw[RT][4];
  int t = threadIdx.x;
  int f0 = blockIdx.x * RT;
  int v0 = blockIdx.y * 1024 + t * 4;
  for (int ri = 0; ri < RT; ri++) xs[ri][t] = nt_emb[(f0 + ri) * D + t];
  __syncthreads();
  float psum[RT];
  for (int ri = 0; ri < RT; ri++) psum[ri] = 0.f;
  if (v0 < V) {
    float acc[RT][4];
#pragma unroll
    for (int ri = 0; ri < RT; ri++)
      for (int j = 0; j < 4; j++) acc[ri][j] = 0.f;
    for (int d4 = 0; d4 < D / 4; d4++) {
      float4 w0 = *(const float4*)(emit_W + (size_t)(4 * d4 + 0) * V + v0);
      float4 w1 = *(const float4*)(emit_W + (size_t)(4 * d4 + 1) * V + v0);
      float4 w2 = *(const float4*)(emit_W + (size_t)(4 * d4 + 2) * V + v0);
      float4 w3 = *(const float4*)(emit_W + (size_t)(4 * d4 + 3) * V + v0);
#pragma unroll
      for (int ri = 0; ri < RT; ri++) {
        float4 xv = *(const float4*)(&xs[ri][4 * d4]);
        acc[ri][0] += xv.x * w0.x + xv.y * w1.x + xv.z * w2.x + xv.w * w3.x;
        acc[ri][1] += xv.x * w0.y + xv.y * w1.y + xv.z * w2.y + xv.w * w3.y;
        acc[ri][2] += xv.x * w0.z + xv.y * w1.z + xv.z * w2.z + xv.w * w3.z;
        acc[ri][3] += xv.x * w0.w + xv.y * w1.w + xv.z * w2.w + xv.w * w3.w;
      }
    }
    float4 eb = *(const float4*)(emit_b + v0);
#pragma unroll
    for (int ri = 0; ri < RT; ri++)
      psum[ri] = __expf(acc[ri][0] + eb.x) + __expf(acc[ri][1] + eb.y) +
                 __expf(acc[ri][2] + eb.z) + __expf(acc[ri][3] + eb.w);
  }
  int lane = t & 63, wid = t >> 6;
  for (int ri = 0; ri < RT; ri++) {
    float v = psum[ri];
    for (int off = 32; off; off >>= 1) v += __shfl_down(v, off, 64);
    if (lane == 0) ldsw[ri][wid] = v;
  }
  __syncthreads();
  if (t < RT) {
    float s = ldsw[t][0] + ldsw[t][1] + ldsw[t][2] + ldsw[t][3];
    partial[(f0 + t) * 16 + blockIdx.y] = s;
  }
}

__global__ void k_logz(const float* __restrict__ partial, float* __restrict__ logZ) {
  int t = blockIdx.x * blockDim.x + threadIdx.x;
  if (t < CF) {
    float s = 0.f;
    for (int ct = 0; ct < 10; ct++) s += partial[t * 16 + ct];
    logZ[t] = __logf(s);
  }
}

// ---------------- terminal scores -> beta diagonal (+ row max) ----------------
__global__ void k_term(const float* __restrict__ nt_emb, const float* __restrict__ emit_W,
                       const float* __restrict__ emit_b, const int* __restrict__ words,
                       const float* __restrict__ split_scores, const float* __restrict__ logZ,
                       float* __restrict__ beta, float* __restrict__ bmax) {
  __shared__ float wcol[D];
  __shared__ float red[256];
  int blk = blockIdx.x;
  int b = blk / NN, n = blk % NN;
  int t = threadIdx.x;
  int w = words[b * NN + n];
  wcol[t] = emit_W[t * V + w];
  __syncthreads();
  float eb = emit_b[w];
  float vmax = -INFINITY;
  for (int f = t; f < CF; f += 256) {
    const float4* xp = (const float4*)(nt_emb + (size_t)f * D);
    float acc = 0.f;
    for (int d4 = 0; d4 < D / 4; d4++) {
      float4 xv = xp[d4];
      acc += xv.x * wcol[4 * d4] + xv.y * wcol[4 * d4 + 1] + xv.z * wcol[4 * d4 + 2] + xv.w * wcol[4 * d4 + 3];
    }
    float val = split_scores[f * 2 + 1] + (acc + eb) - logZ[f];
    beta[(((size_t)n * NN + n) * BB + b) * CF + f] = val;
    vmax = fmaxf(vmax, val);
  }
  red[t] = vmax; __syncthreads();
  for (int off = 128; off; off >>= 1) { if (t < off) red[t] = fmaxf(red[t], red[t + off]); __syncthreads(); }
  if (t == 0) bmax[((size_t)n * NN + n) * BB + b] = red[0];
}

// ---------------- CKY partial: one k-chunk of the sum-domain reduction ----------------
__global__ __launch_bounds__(256) void k_cky_part(const float* __restrict__ egL, const float* __restrict__ egR,
                      const int* __restrict__ lf, const int* __restrict__ rf,
                      const float* __restrict__ beta, const float* __restrict__ bmax,
                      float* __restrict__ partial, int w, int nch, int kcw) {
  __shared__ float EL[KCMAX * CF];
  __shared__ float ER[KCMAX * CF];
  __shared__ float mRs[KCMAX];
  __shared__ float red[256];
  int t = threadIdx.x;
  int blk = blockIdx.x;
  int c = blk % nch;
  int sb = blk / nch;
  int b = sb % BB;
  int s = sb / BB;
  int i = s, j = s + w - 1;
  int wm1 = w - 1;
  int k0 = c * kcw;
  int kc = wm1 - k0; if (kc > kcw) kc = kcw;
  // global max M over ALL k of the span (uniform per block; identical in combine kernel)
  float M = -INFINITY;
  for (int k = 0; k < wm1; k++) {
    float ml = bmax[((size_t)i * NN + (i + k)) * BB + b];
    float mr = bmax[((size_t)(i + k + 1) * NN + j) * BB + b];
    M = fmaxf(M, ml + mr);
  }
  if (t < kc) mRs[t] = bmax[((size_t)(i + k0 + t + 1) * NN + j) * BB + b];
  __syncthreads();
  int tot = kc * CF;
  for (int idx = t; idx < tot; idx += 256) {
    int km = idx / CF;
    int f = idx - km * CF;
    int k = k0 + km;
    float lv = beta[(((size_t)i * NN + (i + k)) * BB + b) * CF + f];
    float rv = beta[(((size_t)(i + k + 1) * NN + j) * BB + b) * CF + f];
    EL[idx] = __expf(lv + mRs[km] - M);
    ER[idx] = __expf(rv - mRs[km]);
  }
  __syncthreads();
  float acc = 0.f;
  if (t < 240) {
    int r = t % CR;
    int a0 = (t / CR) * 24;
#pragma unroll 4
    for (int aa = 0; aa < 24; aa++) {
      int a = a0 + aa;
      float gl = egL[r * CA + a];
      float gr = egR[r * CA + a];
      int fL = rf[r * CA + a];
      int fR = lf[r * CA + a];
      float dA = 0.f, dB = 0.f;
      for (int km = 0; km < kc; km++) {
        dA += EL[km * CF + a] * ER[km * CF + fL];
        dB += EL[km * CF + fR] * ER[km * CF + a];
      }
      acc += gl * dA + gr * dB;
    }
  }
  red[t] = acc;
  __syncthreads();
  if (t < CR) partial[((size_t)sb * PSTRIDE + c) * CR + t] = red[t] + red[t + CR];
}

// ---------------- CKY combine: fixed-order chunk sum + log + NEGV fill + bmax ----------------
__global__ void k_cky_comb(const float* __restrict__ partial, const float* __restrict__ bmaxin,
                           float* __restrict__ beta, float* __restrict__ bmax, int w, int nch) {
  __shared__ float red[128];
  int t = threadIdx.x;
  int sb = blockIdx.x;
  int b = sb % BB;
  int s = sb / BB;
  int i = s, j = s + w - 1;
  int wm1 = w - 1;
  float M = -INFINITY;
  for (int k = 0; k < wm1; k++) {
    float ml = bmaxin[((size_t)i * NN + (i + k)) * BB + b];
    float mr = bmaxin[((size_t)(i + k + 1) * NN + j) * BB + b];
    M = fmaxf(M, ml + mr);
  }
  float val = -INFINITY;
  if (t < CR) {
    float sum = 0.f;
    for (int c = 0; c < nch; c++) sum += partial[((size_t)sb * PSTRIDE + c) * CR + t];
    val = __logf(fmaxf(sum, 1e-45f)) + M;
    beta[(((size_t)i * NN + j) * BB + b) * CF + t] = val;
  }
  for (int f = CR + t; f < CF; f += 128) {
    beta[(((size_t)i * NN + j) * BB + b) * CF + f] = NEGV;
  }
  red[t] = val;
  __syncthreads();
  for (int off = 64; off; off >>= 1) { if (t < off) red[t] = fmaxf(red[t], red[t + off]); __syncthreads(); }
  if (t == 0) bmax[((size_t)i * NN + j) * BB + b] = red[0];
}

// ---------------- final: out[b] = -LSE_f(root_scores[f] + beta[0][N-1][b][f]) ----------------
__global__ void k_final(const float* __restrict__ root_scores, const float* __restrict__ beta,
                        float* __restrict__ out) {
  __shared__ float red[256];
  int b = blockIdx.x;
  int t = threadIdx.x;
  const float* row = &beta[(((size_t)0 * NN + (NN - 1)) * BB + b) * CF];
  float x1 = (t < CF) ? root_scores[t] + row[t] : -INFINITY;
  float x2 = (t + 256 < CF) ? root_scores[t + 256] + row[t + 256] : -INFINITY;
  float mx = fmaxf(x1, x2);
  red[t] = mx; __syncthreads();
  for (int off = 128; off; off >>= 1) { if (t < off) red[t] = fmaxf(red[t], red[t + off]); __syncthreads(); }
  float M = red[0]; __syncthreads();
  float e = ((t < CF) ? __expf(x1 - M) : 0.f) + ((t + 256 < CF) ? __expf(x2 - M) : 0.f);
  red[t] = e; __syncthreads();
  for (int off = 128; off; off >>= 1) { if (t < off) red[t] += red[t + off]; __syncthreads(); }
  if (t == 0) out[b] = -(M + __logf(red[0]));
}

extern "C" void kernel_launch(void* const* d_in, const int* in_sizes, int n_in,
                              void* d_out, int out_size, void* d_ws, size_t ws_size,
                              hipStream_t stream) {
  const float* nt_emb   = (const float*)d_in[1];
  const float* rule_W   = (const float*)d_in[2];
  const float* rule_b   = (const float*)d_in[3];
  const float* root_w   = (const float*)d_in[4];
  const float* root_b   = (const float*)d_in[5];
  const float* root_mask= (const float*)d_in[6];
  const float* split_W1 = (const float*)d_in[7];
  const float* split_b1 = (const float*)d_in[8];
  const float* res_W    = (const float*)d_in[9];
  const float* res_b    = (const float*)d_in[10];
  const float* split_Wo = (const float*)d_in[11];
  const float* split_bo = (const float*)d_in[12];
  const float* emit_W   = (const float*)d_in[13];
  const float* emit_b   = (const float*)d_in[14];
  const int*   words    = (const int*)d_in[15];
  const int*   lfunc    = (const int*)d_in[16];
  const int*   rfunc    = (const int*)d_in[17];

  float* ws = (float*)d_ws;
  float* beta         = ws;                       // 22*22*16*400 = 3,097,600
  float* root_scores  = ws + 3097600;             // 400
  float* split_scores = root_scores + CF;         // 800
  float* egLbuf       = split_scores + 2 * CF;    // 5760
  float* egRbuf       = egLbuf + CR * CA;         // 5760
  float* logZ         = egRbuf + CR * CA;         // 400
  float* partialE     = logZ + CF;                // 6400
  float* bmaxbuf      = partialE + CF * 16;       // 7744
  float* ckyPart      = bmaxbuf + NN * NN * BB;   // 21*16*12*120 = 483,840

  hipLaunchKernelGGL(k_root, dim3(1), dim3(512), 0, stream, root_w, root_b, root_mask, root_scores);
  hipLaunchKernelGGL(k_mlp, dim3(100), dim3(1024), 0, stream, nt_emb, split_W1, split_b1,
                     res_W, res_b, split_Wo, split_bo, split_scores);
  hipLaunchKernelGGL(k_glgr, dim3(CR), dim3(128), 0, stream, rule_W, rule_b, split_scores, egLbuf, egRbuf);
  hipLaunchKernelGGL(k_emit_partial, dim3(CF / RT, 10), dim3(256), 0, stream, nt_emb, emit_W, emit_b, partialE);
  hipLaunchKernelGGL(k_logz, dim3(2), dim3(256), 0, stream, partialE, logZ);
  hipLaunchKernelGGL(k_term, dim3(BB * NN), dim3(256), 0, stream, nt_emb, emit_W, emit_b,
                     words, split_scores, logZ, beta, bmaxbuf);
  for (int w = 2; w <= NN; w++) {
    int S = NN - w + 1;
    int wm1 = w - 1;
    int blocks_sb = S * BB;
    int desired = (blocks_sb >= 240) ? 1 : (240 + blocks_sb - 1) / blocks_sb;
    if (desired > wm1) desired = wm1;
    int kcw = (wm1 + desired - 1) / desired;
    int nch = (wm1 + kcw - 1) / kcw;
    hipLaunchKernelGGL(k_cky_part, dim3(blocks_sb * nch), dim3(256), 0, stream,
                       egLbuf, egRbuf, lfunc, rfunc, beta, bmaxbuf, ckyPart, w, nch, kcw);
    hipLaunchKernelGGL(k_cky_comb, dim3(blocks_sb), dim3(128), 0, stream,
                       ckyPart, bmaxbuf, beta, bmaxbuf, w, nch);
  }
  hipLaunchKernelGGL(k_final, dim3(BB), dim3(256), 0, stream, root_scores, beta, (float*)d_out);
}

// Round 4
// 768.344 us; speedup vs baseline: 1.3275x; 1.3275x over previous
//
#include <hip/hip_runtime.h>
#include <math.h>

#define D 256
#define V 10000
#define BB 16
#define NN 22
#define CF 400
#define CR 120
#define CA 48
#define NEGV -1000000000.0f

// ---------------- root scores: log_softmax(root_mask + root_w + root_b) ----------------
__global__ void k_root(const float* __restrict__ root_w, const float* __restrict__ root_b,
                       const float* __restrict__ root_mask, float* __restrict__ root_scores) {
  __shared__ float red[512];
  int t = threadIdx.x;
  float x = (t < CF) ? (root_mask[t] + root_w[t] + root_b[t]) : -INFINITY;
  red[t] = x; __syncthreads();
  for (int off = 256; off; off >>= 1) { if (t < off) red[t] = fmaxf(red[t], red[t + off]); __syncthreads(); }
  float m = red[0]; __syncthreads();
  red[t] = (t < CF) ? __expf(x - m) : 0.f; __syncthreads();
  for (int off = 256; off; off >>= 1) { if (t < off) red[t] += red[t + off]; __syncthreads(); }
  float z = m + __logf(red[0]);
  if (t < CF) root_scores[t] = x - z;
}

// ---------------- MLP: 4 rows/block, 256 cols, unrolled d-chains ----------------
__global__ __launch_bounds__(256) void k_mlp(const float* __restrict__ nt_emb, const float* __restrict__ W1,
                      const float* __restrict__ b1, const float* __restrict__ resW,
                      const float* __restrict__ resb, const float* __restrict__ Wo,
                      const float* __restrict__ bo, float* __restrict__ split_scores) {
  __shared__ float xs[4][D];
  __shared__ float hs[4][D];
  __shared__ float ts[4][D];
  __shared__ float red0[256], red1[256];
  int t = threadIdx.x;
  int f0 = blockIdx.x * 4;
  for (int ri = 0; ri < 4; ri++) xs[ri][t] = nt_emb[(f0 + ri) * D + t];
  __syncthreads();
  float acc[4];
  for (int ri = 0; ri < 4; ri++) acc[ri] = b1[t];
#pragma unroll 16
  for (int d = 0; d < D; d++) {
    float wv = W1[d * D + t];
    for (int ri = 0; ri < 4; ri++) acc[ri] += xs[ri][d] * wv;
  }
  for (int ri = 0; ri < 4; ri++) hs[ri][t] = acc[ri];
  __syncthreads();
  for (int i = 0; i < 2; i++) {
    for (int ri = 0; ri < 4; ri++) acc[ri] = resb[(i * 2 + 0) * D + t];
    {
      const float* W = resW + (size_t)(i * 2 + 0) * D * D;
#pragma unroll 16
      for (int d = 0; d < D; d++) {
        float wv = W[d * D + t];
        for (int ri = 0; ri < 4; ri++) acc[ri] += hs[ri][d] * wv;
      }
    }
    for (int ri = 0; ri < 4; ri++) ts[ri][t] = fmaxf(acc[ri], 0.f);
    __syncthreads();
    for (int ri = 0; ri < 4; ri++) acc[ri] = resb[(i * 2 + 1) * D + t];
    {
      const float* W = resW + (size_t)(i * 2 + 1) * D * D;
#pragma unroll 16
      for (int d = 0; d < D; d++) {
        float wv = W[d * D + t];
        for (int ri = 0; ri < 4; ri++) acc[ri] += ts[ri][d] * wv;
      }
    }
    __syncthreads();
    for (int ri = 0; ri < 4; ri++) hs[ri][t] = fmaxf(acc[ri], 0.f) + hs[ri][t];
    __syncthreads();
  }
  for (int ri = 0; ri < 4; ri++) {
    red0[t] = hs[ri][t] * Wo[t * 2 + 0];
    red1[t] = hs[ri][t] * Wo[t * 2 + 1];
    __syncthreads();
    for (int off = 128; off; off >>= 1) {
      if (t < off) { red0[t] += red0[t + off]; red1[t] += red1[t + off]; }
      __syncthreads();
    }
    if (t == 0) {
      float s0 = red0[0] + bo[0], s1 = red1[0] + bo[1];
      float m = fmaxf(s0, s1);
      float z = m + __logf(__expf(s0 - m) + __expf(s1 - m));
      split_scores[(f0 + ri) * 2 + 0] = s0 - z;
      split_scores[(f0 + ri) * 2 + 1] = s1 - z;
    }
    __syncthreads();
  }
}

// ---------------- egL/egR = exp(rule log-softmax + split0)  (fake_emb is identity) ----------------
__global__ void k_glgr(const float* __restrict__ rule_W, const float* __restrict__ rule_b,
                       const float* __restrict__ split_scores,
                       float* __restrict__ egL, float* __restrict__ egR) {
  __shared__ float red[128];
  int r = blockIdx.x;
  int t = threadIdx.x;
  float x = (t < 96) ? (rule_W[t * CR + r] + rule_b[t]) : -INFINITY;
  red[t] = x; __syncthreads();
  for (int off = 64; off; off >>= 1) { if (t < off) red[t] = fmaxf(red[t], red[t + off]); __syncthreads(); }
  float m = red[0]; __syncthreads();
  red[t] = (t < 96) ? __expf(x - m) : 0.f; __syncthreads();
  for (int off = 64; off; off >>= 1) { if (t < off) red[t] += red[t + off]; __syncthreads(); }
  float z = m + __logf(red[0]);
  float s0 = split_scores[r * 2 + 0];
  if (t < CA) egL[r * CA + t] = __expf((x - z) + s0);
  else if (t < 96) egR[r * CA + (t - CA)] = __expf((x - z) + s0);
}

// ---------------- emission: per-row partial sum of exp(logits), float4 over v, RT=16 ----------------
#define RT 16
__global__ __launch_bounds__(256) void k_emit_partial(const float* __restrict__ nt_emb,
                               const float* __restrict__ emit_W,
                               const float* __restrict__ emit_b, float* __restrict__ partial) {
  __shared__ float xs[RT][D];
  __shared__ float ldsw[RT][4];
  int t = threadIdx.x;
  int f0 = blockIdx.x * RT;
  int v0 = blockIdx.y * 1024 + t * 4;
  for (int ri = 0; ri < RT; ri++) xs[ri][t] = nt_emb[(f0 + ri) * D + t];
  __syncthreads();
  float psum[RT];
  for (int ri = 0; ri < RT; ri++) psum[ri] = 0.f;
  if (v0 < V) {
    float acc[RT][4];
#pragma unroll
    for (int ri = 0; ri < RT; ri++)
      for (int j = 0; j < 4; j++) acc[ri][j] = 0.f;
    for (int d4 = 0; d4 < D / 4; d4++) {
      float4 w0 = *(const float4*)(emit_W + (size_t)(4 * d4 + 0) * V + v0);
      float4 w1 = *(const float4*)(emit_W + (size_t)(4 * d4 + 1) * V + v0);
      float4 w2 = *(const float4*)(emit_W + (size_t)(4 * d4 + 2) * V + v0);
      float4 w3 = *(const float4*)(emit_W + (size_t)(4 * d4 + 3) * V + v0);
#pragma unroll
      for (int ri = 0; ri < RT; ri++) {
        float4 xv = *(const float4*)(&xs[ri][4 * d4]);
        acc[ri][0] += xv.x * w0.x + xv.y * w1.x + xv.z * w2.x + xv.w * w3.x;
        acc[ri][1] += xv.x * w0.y + xv.y * w1.y + xv.z * w2.y + xv.w * w3.y;
        acc[ri][2] += xv.x * w0.z + xv.y * w1.z + xv.z * w2.z + xv.w * w3.z;
        acc[ri][3] += xv.x * w0.w + xv.y * w1.w + xv.z * w2.w + xv.w * w3.w;
      }
    }
    float4 eb = *(const float4*)(emit_b + v0);
#pragma unroll
    for (int ri = 0; ri < RT; ri++)
      psum[ri] = __expf(acc[ri][0] + eb.x) + __expf(acc[ri][1] + eb.y) +
                 __expf(acc[ri][2] + eb.z) + __expf(acc[ri][3] + eb.w);
  }
  int lane = t & 63, wid = t >> 6;
  for (int ri = 0; ri < RT; ri++) {
    float v = psum[ri];
    for (int off = 32; off; off >>= 1) v += __shfl_down(v, off, 64);
    if (lane == 0) ldsw[ri][wid] = v;
  }
  __syncthreads();
  if (t < RT) {
    float s = ldsw[t][0] + ldsw[t][1] + ldsw[t][2] + ldsw[t][3];
    partial[(f0 + t) * 16 + blockIdx.y] = s;
  }
}

__global__ void k_logz(const float* __restrict__ partial, float* __restrict__ logZ) {
  int t = blockIdx.x * blockDim.x + threadIdx.x;
  if (t < CF) {
    float s = 0.f;
    for (int ct = 0; ct < 10; ct++) s += partial[t * 16 + ct];
    logZ[t] = __logf(s);
  }
}

// ---------------- terminal scores -> beta diagonal (+ row max), wave-per-row coalesced ----------------
__global__ __launch_bounds__(512) void k_term(const float* __restrict__ nt_emb,
                       const float* __restrict__ emit_W,
                       const float* __restrict__ emit_b, const int* __restrict__ words,
                       const float* __restrict__ split_scores, const float* __restrict__ logZ,
                       float* __restrict__ beta, float* __restrict__ bmax) {
  __shared__ float redw[8];
  int blk = blockIdx.x;
  int b = blk / NN, n = blk % NN;
  int t = threadIdx.x;
  int lane = t & 63, wid = t >> 6;   // 8 waves, 50 rows each
  int w = words[b * NN + n];
  // lane d holds weight dims 4d..4d+3 in registers
  float wc0 = emit_W[(size_t)(4 * lane + 0) * V + w];
  float wc1 = emit_W[(size_t)(4 * lane + 1) * V + w];
  float wc2 = emit_W[(size_t)(4 * lane + 2) * V + w];
  float wc3 = emit_W[(size_t)(4 * lane + 3) * V + w];
  float eb = emit_b[w];
  float* dst = &beta[(((size_t)n * NN + n) * BB + b) * CF];
  float vmax = -INFINITY;
  int fbase = wid * 50;
  for (int k = 0; k < 50; k += 2) {
    int f0 = fbase + k, f1 = f0 + 1;
    float4 xa = *(const float4*)(nt_emb + (size_t)f0 * D + 4 * lane);
    float4 xb = *(const float4*)(nt_emb + (size_t)f1 * D + 4 * lane);
    float va = xa.x * wc0 + xa.y * wc1 + xa.z * wc2 + xa.w * wc3;
    float vb = xb.x * wc0 + xb.y * wc1 + xb.z * wc2 + xb.w * wc3;
    for (int off = 32; off; off >>= 1) {
      va += __shfl_down(va, off, 64);
      vb += __shfl_down(vb, off, 64);
    }
    if (lane == 0) {
      float fa = split_scores[f0 * 2 + 1] + (va + eb) - logZ[f0];
      float fb = split_scores[f1 * 2 + 1] + (vb + eb) - logZ[f1];
      dst[f0] = fa; dst[f1] = fb;
      vmax = fmaxf(vmax, fmaxf(fa, fb));
    }
  }
  if (lane == 0) redw[wid] = vmax;
  __syncthreads();
  if (t == 0) {
    float m = redw[0];
    for (int i = 1; i < 8; i++) m = fmaxf(m, redw[i]);
    bmax[((size_t)n * NN + n) * BB + b] = m;
  }
}

// ---------------- CKY step for width w (sum-domain, factored LSE) ----------------
__global__ __launch_bounds__(256) void k_cky(const float* __restrict__ egL, const float* __restrict__ egR,
                      const int* __restrict__ lf, const int* __restrict__ rf,
                      float* __restrict__ beta, float* __restrict__ bmax, int w) {
  __shared__ float EL[21 * CF];
  __shared__ float ER[21 * CF];
  __shared__ float mR[21];
  __shared__ float sM[21];
  __shared__ float red[256];
  __shared__ float Msh;
  int t = threadIdx.x;
  int s = blockIdx.x / BB;
  int b = blockIdx.x % BB;
  int i = s, j = s + w - 1;
  int wm1 = w - 1;
  if (t < wm1) {
    float ml = bmax[((size_t)i * NN + (i + t)) * BB + b];
    float mr = bmax[((size_t)(i + t + 1) * NN + j) * BB + b];
    mR[t] = mr;
    sM[t] = ml + mr;
  }
  __syncthreads();
  if (t == 0) {
    float M = sM[0];
    for (int k = 1; k < wm1; k++) M = fmaxf(M, sM[k]);
    Msh = M;
  }
  __syncthreads();
  float M = Msh;
  int tot = wm1 * CF;
  for (int idx = t; idx < tot; idx += 256) {
    int km = idx / CF;
    int f = idx - km * CF;
    float lv = beta[(((size_t)i * NN + (i + km)) * BB + b) * CF + f];
    float rv = beta[(((size_t)(i + km + 1) * NN + j) * BB + b) * CF + f];
    EL[idx] = __expf(lv + mR[km] - M);
    ER[idx] = __expf(rv - mR[km]);
  }
  __syncthreads();
  float acc = 0.f;
  if (t < 240) {
    int r = t % CR;
    int a0 = (t / CR) * 24;
#pragma unroll 4
    for (int aa = 0; aa < 24; aa++) {
      int a = a0 + aa;
      float gl = egL[r * CA + a];
      float gr = egR[r * CA + a];
      int fL = rf[r * CA + a];
      int fR = lf[r * CA + a];
      float dA = 0.f, dB = 0.f;
      for (int km = 0; km < wm1; km++) {
        dA += EL[km * CF + a] * ER[km * CF + fL];
        dB += EL[km * CF + fR] * ER[km * CF + a];
      }
      acc += gl * dA + gr * dB;
    }
  }
  red[t] = acc;
  __syncthreads();
  float val = -INFINITY;
  if (t < CR) {
    float sum = red[t] + red[t + CR];
    val = __logf(fmaxf(sum, 1e-45f)) + M;
    beta[(((size_t)i * NN + j) * BB + b) * CF + t] = val;
  }
  __syncthreads();
  red[t] = val;
  __syncthreads();
  for (int off = 128; off; off >>= 1) { if (t < off) red[t] = fmaxf(red[t], red[t + off]); __syncthreads(); }
  if (t == 0) bmax[((size_t)i * NN + j) * BB + b] = red[0];
  for (int f = CR + t; f < CF; f += 256) {
    beta[(((size_t)i * NN + j) * BB + b) * CF + f] = NEGV;
  }
}

// ---------------- final: out[b] = -LSE_f(root_scores[f] + beta[0][N-1][b][f]) ----------------
__global__ void k_final(const float* __restrict__ root_scores, const float* __restrict__ beta,
                        float* __restrict__ out) {
  __shared__ float red[256];
  int b = blockIdx.x;
  int t = threadIdx.x;
  const float* row = &beta[(((size_t)0 * NN + (NN - 1)) * BB + b) * CF];
  float x1 = (t < CF) ? root_scores[t] + row[t] : -INFINITY;
  float x2 = (t + 256 < CF) ? root_scores[t + 256] + row[t + 256] : -INFINITY;
  float mx = fmaxf(x1, x2);
  red[t] = mx; __syncthreads();
  for (int off = 128; off; off >>= 1) { if (t < off) red[t] = fmaxf(red[t], red[t + off]); __syncthreads(); }
  float M = red[0]; __syncthreads();
  float e = ((t < CF) ? __expf(x1 - M) : 0.f) + ((t + 256 < CF) ? __expf(x2 - M) : 0.f);
  red[t] = e; __syncthreads();
  for (int off = 128; off; off >>= 1) { if (t < off) red[t] += red[t + off]; __syncthreads(); }
  if (t == 0) out[b] = -(M + __logf(red[0]));
}

extern "C" void kernel_launch(void* const* d_in, const int* in_sizes, int n_in,
                              void* d_out, int out_size, void* d_ws, size_t ws_size,
                              hipStream_t stream) {
  const float* nt_emb   = (const float*)d_in[1];
  const float* rule_W   = (const float*)d_in[2];
  const float* rule_b   = (const float*)d_in[3];
  const float* root_w   = (const float*)d_in[4];
  const float* root_b   = (const float*)d_in[5];
  const float* root_mask= (const float*)d_in[6];
  const float* split_W1 = (const float*)d_in[7];
  const float* split_b1 = (const float*)d_in[8];
  const float* res_W    = (const float*)d_in[9];
  const float* res_b    = (const float*)d_in[10];
  const float* split_Wo = (const float*)d_in[11];
  const float* split_bo = (const float*)d_in[12];
  const float* emit_W   = (const float*)d_in[13];
  const float* emit_b   = (const float*)d_in[14];
  const int*   words    = (const int*)d_in[15];
  const int*   lfunc    = (const int*)d_in[16];
  const int*   rfunc    = (const int*)d_in[17];

  float* ws = (float*)d_ws;
  float* beta         = ws;                       // 22*22*16*400 = 3,097,600
  float* root_scores  = ws + 3097600;             // 400
  float* split_scores = root_scores + CF;         // 800
  float* egLbuf       = split_scores + 2 * CF;    // 5760
  float* egRbuf       = egLbuf + CR * CA;         // 5760
  float* logZ         = egRbuf + CR * CA;         // 400
  float* partialE     = logZ + CF;                // 6400
  float* bmaxbuf      = partialE + CF * 16;       // 7744

  hipLaunchKernelGGL(k_root, dim3(1), dim3(512), 0, stream, root_w, root_b, root_mask, root_scores);
  hipLaunchKernelGGL(k_mlp, dim3(100), dim3(256), 0, stream, nt_emb, split_W1, split_b1,
                     res_W, res_b, split_Wo, split_bo, split_scores);
  hipLaunchKernelGGL(k_glgr, dim3(CR), dim3(128), 0, stream, rule_W, rule_b, split_scores, egLbuf, egRbuf);
  hipLaunchKernelGGL(k_emit_partial, dim3(CF / RT, 10), dim3(256), 0, stream, nt_emb, emit_W, emit_b, partialE);
  hipLaunchKernelGGL(k_logz, dim3(2), dim3(256), 0, stream, partialE, logZ);
  hipLaunchKernelGGL(k_term, dim3(BB * NN), dim3(512), 0, stream, nt_emb, emit_W, emit_b,
                     words, split_scores, logZ, beta, bmaxbuf);
  for (int w = 2; w <= NN; w++) {
    int S = NN - w + 1;
    hipLaunchKernelGGL(k_cky, dim3(S * BB), dim3(256), 0, stream, egLbuf, egRbuf, lfunc, rfunc,
                       beta, bmaxbuf, w);
  }
  hipLaunchKernelGGL(k_final, dim3(BB), dim3(256), 0, stream, root_scores, beta, (float*)d_out);
}

// Round 5
// 597.891 us; speedup vs baseline: 1.7060x; 1.2851x over previous
//
#include <hip/hip_runtime.h>
#include <math.h>

#define D 256
#define V 10000
#define BB 16
#define NN 22
#define CF 400
#define CR 120
#define CA 48
#define NEGV -1000000000.0f

// ---------------- root scores: log_softmax(root_mask + root_w + root_b) ----------------
__global__ void k_root(const float* __restrict__ root_w, const float* __restrict__ root_b,
                       const float* __restrict__ root_mask, float* __restrict__ root_scores) {
  __shared__ float red[512];
  int t = threadIdx.x;
  float x = (t < CF) ? (root_mask[t] + root_w[t] + root_b[t]) : -INFINITY;
  red[t] = x; __syncthreads();
  for (int off = 256; off; off >>= 1) { if (t < off) red[t] = fmaxf(red[t], red[t + off]); __syncthreads(); }
  float m = red[0]; __syncthreads();
  red[t] = (t < CF) ? __expf(x - m) : 0.f; __syncthreads();
  for (int off = 256; off; off >>= 1) { if (t < off) red[t] += red[t + off]; __syncthreads(); }
  float z = m + __logf(red[0]);
  if (t < CF) root_scores[t] = x - z;
}

// ---------------- MLP: 2 rows/block, 256 cols, unrolled d-chains ----------------
__global__ __launch_bounds__(256) void k_mlp(const float* __restrict__ nt_emb, const float* __restrict__ W1,
                      const float* __restrict__ b1, const float* __restrict__ resW,
                      const float* __restrict__ resb, const float* __restrict__ Wo,
                      const float* __restrict__ bo, float* __restrict__ split_scores) {
  __shared__ float xs[2][D];
  __shared__ float hs[2][D];
  __shared__ float ts[2][D];
  __shared__ float red0[256], red1[256];
  int t = threadIdx.x;
  int f0 = blockIdx.x * 2;
  for (int ri = 0; ri < 2; ri++) xs[ri][t] = nt_emb[(f0 + ri) * D + t];
  __syncthreads();
  float acc[2];
  for (int ri = 0; ri < 2; ri++) acc[ri] = b1[t];
#pragma unroll 16
  for (int d = 0; d < D; d++) {
    float wv = W1[d * D + t];
    for (int ri = 0; ri < 2; ri++) acc[ri] += xs[ri][d] * wv;
  }
  for (int ri = 0; ri < 2; ri++) hs[ri][t] = acc[ri];
  __syncthreads();
  for (int i = 0; i < 2; i++) {
    for (int ri = 0; ri < 2; ri++) acc[ri] = resb[(i * 2 + 0) * D + t];
    {
      const float* W = resW + (size_t)(i * 2 + 0) * D * D;
#pragma unroll 16
      for (int d = 0; d < D; d++) {
        float wv = W[d * D + t];
        for (int ri = 0; ri < 2; ri++) acc[ri] += hs[ri][d] * wv;
      }
    }
    for (int ri = 0; ri < 2; ri++) ts[ri][t] = fmaxf(acc[ri], 0.f);
    __syncthreads();
    for (int ri = 0; ri < 2; ri++) acc[ri] = resb[(i * 2 + 1) * D + t];
    {
      const float* W = resW + (size_t)(i * 2 + 1) * D * D;
#pragma unroll 16
      for (int d = 0; d < D; d++) {
        float wv = W[d * D + t];
        for (int ri = 0; ri < 2; ri++) acc[ri] += ts[ri][d] * wv;
      }
    }
    __syncthreads();
    for (int ri = 0; ri < 2; ri++) hs[ri][t] = fmaxf(acc[ri], 0.f) + hs[ri][t];
    __syncthreads();
  }
  for (int ri = 0; ri < 2; ri++) {
    red0[t] = hs[ri][t] * Wo[t * 2 + 0];
    red1[t] = hs[ri][t] * Wo[t * 2 + 1];
    __syncthreads();
    for (int off = 128; off; off >>= 1) {
      if (t < off) { red0[t] += red0[t + off]; red1[t] += red1[t + off]; }
      __syncthreads();
    }
    if (t == 0) {
      float s0 = red0[0] + bo[0], s1 = red1[0] + bo[1];
      float m = fmaxf(s0, s1);
      float z = m + __logf(__expf(s0 - m) + __expf(s1 - m));
      split_scores[(f0 + ri) * 2 + 0] = s0 - z;
      split_scores[(f0 + ri) * 2 + 1] = s1 - z;
    }
    __syncthreads();
  }
}

// ---------------- egL/egR = exp(rule log-softmax + split0)  (fake_emb is identity) ----------------
__global__ void k_glgr(const float* __restrict__ rule_W, const float* __restrict__ rule_b,
                       const float* __restrict__ split_scores,
                       float* __restrict__ egL, float* __restrict__ egR) {
  __shared__ float red[128];
  int r = blockIdx.x;
  int t = threadIdx.x;
  float x = (t < 96) ? (rule_W[t * CR + r] + rule_b[t]) : -INFINITY;
  red[t] = x; __syncthreads();
  for (int off = 64; off; off >>= 1) { if (t < off) red[t] = fmaxf(red[t], red[t + off]); __syncthreads(); }
  float m = red[0]; __syncthreads();
  red[t] = (t < 96) ? __expf(x - m) : 0.f; __syncthreads();
  for (int off = 64; off; off >>= 1) { if (t < off) red[t] += red[t + off]; __syncthreads(); }
  float z = m + __logf(red[0]);
  float s0 = split_scores[r * 2 + 0];
  if (t < CA) egL[r * CA + t] = __expf((x - z) + s0);
  else if (t < 96) egR[r * CA + (t - CA)] = __expf((x - z) + s0);
}

// ---------------- emission: per-row partial sum of exp(logits), float4 over v, RT=8 ----------------
#define RT 8
__global__ __launch_bounds__(256) void k_emit_partial(const float* __restrict__ nt_emb,
                               const float* __restrict__ emit_W,
                               const float* __restrict__ emit_b, float* __restrict__ partial) {
  __shared__ float xs[RT][D];
  __shared__ float ldsw[RT][4];
  int t = threadIdx.x;
  int f0 = blockIdx.x * RT;
  int v0 = blockIdx.y * 1024 + t * 4;
  for (int ri = 0; ri < RT; ri++) xs[ri][t] = nt_emb[(f0 + ri) * D + t];
  __syncthreads();
  float psum[RT];
  for (int ri = 0; ri < RT; ri++) psum[ri] = 0.f;
  if (v0 < V) {
    float acc[RT][4];
#pragma unroll
    for (int ri = 0; ri < RT; ri++)
      for (int j = 0; j < 4; j++) acc[ri][j] = 0.f;
    for (int d4 = 0; d4 < D / 4; d4++) {
      float4 w0 = *(const float4*)(emit_W + (size_t)(4 * d4 + 0) * V + v0);
      float4 w1 = *(const float4*)(emit_W + (size_t)(4 * d4 + 1) * V + v0);
      float4 w2 = *(const float4*)(emit_W + (size_t)(4 * d4 + 2) * V + v0);
      float4 w3 = *(const float4*)(emit_W + (size_t)(4 * d4 + 3) * V + v0);
#pragma unroll
      for (int ri = 0; ri < RT; ri++) {
        float4 xv = *(const float4*)(&xs[ri][4 * d4]);
        acc[ri][0] += xv.x * w0.x + xv.y * w1.x + xv.z * w2.x + xv.w * w3.x;
        acc[ri][1] += xv.x * w0.y + xv.y * w1.y + xv.z * w2.y + xv.w * w3.y;
        acc[ri][2] += xv.x * w0.z + xv.y * w1.z + xv.z * w2.z + xv.w * w3.z;
        acc[ri][3] += xv.x * w0.w + xv.y * w1.w + xv.z * w2.w + xv.w * w3.w;
      }
    }
    float4 eb = *(const float4*)(emit_b + v0);
#pragma unroll
    for (int ri = 0; ri < RT; ri++)
      psum[ri] = __expf(acc[ri][0] + eb.x) + __expf(acc[ri][1] + eb.y) +
                 __expf(acc[ri][2] + eb.z) + __expf(acc[ri][3] + eb.w);
  }
  int lane = t & 63, wid = t >> 6;
  for (int ri = 0; ri < RT; ri++) {
    float v = psum[ri];
    for (int off = 32; off; off >>= 1) v += __shfl_down(v, off, 64);
    if (lane == 0) ldsw[ri][wid] = v;
  }
  __syncthreads();
  if (t < RT) {
    float s = ldsw[t][0] + ldsw[t][1] + ldsw[t][2] + ldsw[t][3];
    partial[(f0 + t) * 16 + blockIdx.y] = s;
  }
}

__global__ void k_logz(const float* __restrict__ partial, float* __restrict__ logZ) {
  int t = blockIdx.x * blockDim.x + threadIdx.x;
  if (t < CF) {
    float s = 0.f;
    for (int ct = 0; ct < 10; ct++) s += partial[t * 16 + ct];
    logZ[t] = __logf(s);
  }
}

// ---------------- terminal scores -> term[n][b][CF] (+ row max), wave-per-row coalesced ----------------
__global__ __launch_bounds__(512) void k_term(const float* __restrict__ nt_emb,
                       const float* __restrict__ emit_W,
                       const float* __restrict__ emit_b, const int* __restrict__ words,
                       const float* __restrict__ split_scores, const float* __restrict__ logZ,
                       float* __restrict__ term, float* __restrict__ bmax) {
  __shared__ float redw[8];
  int blk = blockIdx.x;
  int b = blk / NN, n = blk % NN;
  int t = threadIdx.x;
  int lane = t & 63, wid = t >> 6;   // 8 waves, 50 rows each
  int w = words[b * NN + n];
  float wc0 = emit_W[(size_t)(4 * lane + 0) * V + w];
  float wc1 = emit_W[(size_t)(4 * lane + 1) * V + w];
  float wc2 = emit_W[(size_t)(4 * lane + 2) * V + w];
  float wc3 = emit_W[(size_t)(4 * lane + 3) * V + w];
  float eb = emit_b[w];
  float* dst = &term[((size_t)n * BB + b) * CF];
  float vmax = -INFINITY;
  int fbase = wid * 50;
  for (int k = 0; k < 50; k += 2) {
    int f0 = fbase + k, f1 = f0 + 1;
    float4 xa = *(const float4*)(nt_emb + (size_t)f0 * D + 4 * lane);
    float4 xb = *(const float4*)(nt_emb + (size_t)f1 * D + 4 * lane);
    float va = xa.x * wc0 + xa.y * wc1 + xa.z * wc2 + xa.w * wc3;
    float vb = xb.x * wc0 + xb.y * wc1 + xb.z * wc2 + xb.w * wc3;
    for (int off = 32; off; off >>= 1) {
      va += __shfl_down(va, off, 64);
      vb += __shfl_down(vb, off, 64);
    }
    if (lane == 0) {
      float fa = split_scores[f0 * 2 + 1] + (va + eb) - logZ[f0];
      float fb = split_scores[f1 * 2 + 1] + (vb + eb) - logZ[f1];
      dst[f0] = fa; dst[f1] = fb;
      vmax = fmaxf(vmax, fmaxf(fa, fb));
    }
  }
  if (lane == 0) redw[wid] = vmax;
  __syncthreads();
  if (t == 0) {
    float m = redw[0];
    for (int i = 1; i < 8; i++) m = fmaxf(m, redw[i]);
    bmax[((size_t)n * NN + n) * BB + b] = m;
  }
}

// ---------------- CKY step for width w: compact beta (CR) + diagonal term (CF) ----------------
__global__ __launch_bounds__(512) void k_cky(const float* __restrict__ egL, const float* __restrict__ egR,
                      const int* __restrict__ lf, const int* __restrict__ rf,
                      const float* __restrict__ term,
                      float* __restrict__ beta, float* __restrict__ bmax, int w) {
  __shared__ float ELd[CF + 1];
  __shared__ float ERd[CF + 1];
  __shared__ float ELc[20 * (CR + 1)];
  __shared__ float ERc[20 * (CR + 1)];
  __shared__ float mR[21];
  __shared__ float sM[21];
  __shared__ float red[512];
  __shared__ float Msh;
  int t = threadIdx.x;
  int s = blockIdx.x / BB;
  int b = blockIdx.x % BB;
  int i = s, j = s + w - 1;
  int wm1 = w - 1;
  if (t < wm1) {
    float ml = bmax[((size_t)i * NN + (i + t)) * BB + b];
    float mr = bmax[((size_t)(i + t + 1) * NN + j) * BB + b];
    mR[t] = mr;
    sM[t] = ml + mr;
  }
  __syncthreads();
  if (t == 0) {
    float M = sM[0];
    for (int k = 1; k < wm1; k++) M = fmaxf(M, sM[k]);
    Msh = M;
  }
  __syncthreads();
  float M = Msh;
  // diagonal slices: left child at km=0 is term[i]; right child at km=w-2 is term[j]
  for (int f = t; f < CF; f += 512) {
    ELd[f] = __expf(term[((size_t)i * BB + b) * CF + f] + mR[0] - M);
    ERd[f] = __expf(term[((size_t)j * BB + b) * CF + f] - mR[w - 2]);
  }
  // compact slices
  int totc = (w - 2) * CR;
  for (int idx = t; idx < totc; idx += 512) {
    int km1 = idx / CR;          // 0..w-3
    int f = idx - km1 * CR;
    int kmL = km1 + 1;           // EL slice km = 1..w-2
    int kmR = km1;               // ER slice km = 0..w-3
    ELc[km1 * (CR + 1) + f] = __expf(beta[(((size_t)i * NN + (i + kmL)) * BB + b) * CR + f] + mR[kmL] - M);
    ERc[km1 * (CR + 1) + f] = __expf(beta[(((size_t)(i + kmR + 1) * NN + j) * BB + b) * CR + f] - mR[kmR]);
  }
  if (t < w - 2) { ELc[t * (CR + 1) + CR] = 0.f; ERc[t * (CR + 1) + CR] = 0.f; }
  __syncthreads();
  float acc = 0.f;
  if (t < 480) {
    int r = t % CR;
    int a0 = (t / CR) * 12;
#pragma unroll 4
    for (int aa = 0; aa < 12; aa++) {
      int a = a0 + aa;
      float gl = egL[r * CA + a];
      float gr = egR[r * CA + a];
      int fL = rf[r * CA + a];           // gather into right child (dA)
      int fR = lf[r * CA + a];           // gather into left child  (dB)
      int fLc = min(fL, CR);
      int fRc = min(fR, CR);
      float dA = 0.f, dB = 0.f;
      // km = 0: left diagonal
      if (w == 2) {
        dA += ELd[a] * ERd[fL];
        dB += ELd[fR] * ERd[a];
      } else {
        dA += ELd[a] * ERc[fLc];
        dB += ELd[fR] * ERc[a];
      }
      // middle km = 1 .. w-3: both compact
      for (int km = 1; km <= w - 3; km++) {
        const float* Lc = &ELc[(km - 1) * (CR + 1)];
        const float* Rc = &ERc[km * (CR + 1)];
        dA += Lc[a] * Rc[fLc];
        dB += Lc[fRc] * Rc[a];
      }
      // km = w-2 (w>2): right diagonal
      if (w > 2) {
        const float* Lc = &ELc[(w - 3) * (CR + 1)];
        dA += Lc[a] * ERd[fL];
        dB += Lc[fRc] * ERd[a];
      }
      acc += gl * dA + gr * dB;
    }
  }
  red[t] = acc;
  __syncthreads();
  float val = -INFINITY;
  if (t < CR) {
    float sum = red[t] + red[t + CR] + red[t + 2 * CR] + red[t + 3 * CR];
    val = __logf(fmaxf(sum, 1e-45f)) + M;
    beta[(((size_t)i * NN + j) * BB + b) * CR + t] = val;
  }
  __syncthreads();
  red[t] = val;
  __syncthreads();
  for (int off = 256; off; off >>= 1) { if (t < off) red[t] = fmaxf(red[t], red[t + off]); __syncthreads(); }
  if (t == 0) bmax[((size_t)i * NN + j) * BB + b] = red[0];
}

// ---------------- final: out[b] = -LSE_f(root_scores[f] + beta[0][N-1][b][f<CR]) ----------------
__global__ void k_final(const float* __restrict__ root_scores, const float* __restrict__ beta,
                        float* __restrict__ out) {
  __shared__ float red[128];
  int b = blockIdx.x;
  int t = threadIdx.x;
  const float* row = &beta[(((size_t)0 * NN + (NN - 1)) * BB + b) * CR];
  float x1 = (t < CR) ? root_scores[t] + row[t] : -INFINITY;
  red[t] = x1; __syncthreads();
  for (int off = 64; off; off >>= 1) { if (t < off) red[t] = fmaxf(red[t], red[t + off]); __syncthreads(); }
  float M = red[0]; __syncthreads();
  red[t] = (t < CR) ? __expf(x1 - M) : 0.f; __syncthreads();
  for (int off = 64; off; off >>= 1) { if (t < off) red[t] += red[t + off]; __syncthreads(); }
  if (t == 0) out[b] = -(M + __logf(red[0]));
}

extern "C" void kernel_launch(void* const* d_in, const int* in_sizes, int n_in,
                              void* d_out, int out_size, void* d_ws, size_t ws_size,
                              hipStream_t stream) {
  const float* nt_emb   = (const float*)d_in[1];
  const float* rule_W   = (const float*)d_in[2];
  const float* rule_b   = (const float*)d_in[3];
  const float* root_w   = (const float*)d_in[4];
  const float* root_b   = (const float*)d_in[5];
  const float* root_mask= (const float*)d_in[6];
  const float* split_W1 = (const float*)d_in[7];
  const float* split_b1 = (const float*)d_in[8];
  const float* res_W    = (const float*)d_in[9];
  const float* res_b    = (const float*)d_in[10];
  const float* split_Wo = (const float*)d_in[11];
  const float* split_bo = (const float*)d_in[12];
  const float* emit_W   = (const float*)d_in[13];
  const float* emit_b   = (const float*)d_in[14];
  const int*   words    = (const int*)d_in[15];
  const int*   lfunc    = (const int*)d_in[16];
  const int*   rfunc    = (const int*)d_in[17];

  float* ws = (float*)d_ws;
  float* term         = ws;                        // 22*16*400   = 140,800
  float* beta         = term + NN * BB * CF;       // 22*22*16*120 = 929,280
  float* root_scores  = beta + NN * NN * BB * CR;  // 400
  float* split_scores = root_scores + CF;          // 800
  float* egLbuf       = split_scores + 2 * CF;     // 5760
  float* egRbuf       = egLbuf + CR * CA;          // 5760
  float* logZ         = egRbuf + CR * CA;          // 400
  float* partialE     = logZ + CF;                 // 6400
  float* bmaxbuf      = partialE + CF * 16;        // 7744

  hipLaunchKernelGGL(k_root, dim3(1), dim3(512), 0, stream, root_w, root_b, root_mask, root_scores);
  hipLaunchKernelGGL(k_mlp, dim3(CF / 2), dim3(256), 0, stream, nt_emb, split_W1, split_b1,
                     res_W, res_b, split_Wo, split_bo, split_scores);
  hipLaunchKernelGGL(k_glgr, dim3(CR), dim3(128), 0, stream, rule_W, rule_b, split_scores, egLbuf, egRbuf);
  hipLaunchKernelGGL(k_emit_partial, dim3(CF / RT, 10), dim3(256), 0, stream, nt_emb, emit_W, emit_b, partialE);
  hipLaunchKernelGGL(k_logz, dim3(2), dim3(256), 0, stream, partialE, logZ);
  hipLaunchKernelGGL(k_term, dim3(BB * NN), dim3(512), 0, stream, nt_emb, emit_W, emit_b,
                     words, split_scores, logZ, term, bmaxbuf);
  for (int w = 2; w <= NN; w++) {
    int S = NN - w + 1;
    hipLaunchKernelGGL(k_cky, dim3(S * BB), dim3(512), 0, stream, egLbuf, egRbuf, lfunc, rfunc,
                       term, beta, bmaxbuf, w);
  }
  hipLaunchKernelGGL(k_final, dim3(BB), dim3(128), 0, stream, root_scores, beta, (float*)d_out);
}

// Round 6
// 375.102 us; speedup vs baseline: 2.7193x; 1.5939x over previous
//
#include <hip/hip_runtime.h>
#include <math.h>

#define D 256
#define V 10000
#define BB 16
#define NN 22
#define CF 400
#define CR 120
#define CA 48
#define CRP 121     // compact rows incl zero slot at 120
#define PADF 20     // LDS row pad (floats) -> 80B, cycles all 32 banks, 16B-aligned

// ---------------- root scores: log_softmax(root_mask + root_w + root_b) ----------------
__global__ void k_root(const float* __restrict__ root_w, const float* __restrict__ root_b,
                       const float* __restrict__ root_mask, float* __restrict__ root_scores) {
  __shared__ float red[512];
  int t = threadIdx.x;
  float x = (t < CF) ? (root_mask[t] + root_w[t] + root_b[t]) : -INFINITY;
  red[t] = x; __syncthreads();
  for (int off = 256; off; off >>= 1) { if (t < off) red[t] = fmaxf(red[t], red[t + off]); __syncthreads(); }
  float m = red[0]; __syncthreads();
  red[t] = (t < CF) ? __expf(x - m) : 0.f; __syncthreads();
  for (int off = 256; off; off >>= 1) { if (t < off) red[t] += red[t + off]; __syncthreads(); }
  float z = m + __logf(red[0]);
  if (t < CF) root_scores[t] = x - z;
}

// ---------------- MLP: 2 rows/block, 512 threads = 2 d-halves x 256 cols ----------------
__global__ __launch_bounds__(512) void k_mlp(const float* __restrict__ nt_emb, const float* __restrict__ W1,
                      const float* __restrict__ b1, const float* __restrict__ resW,
                      const float* __restrict__ resb, const float* __restrict__ Wo,
                      const float* __restrict__ bo, float* __restrict__ split_scores) {
  __shared__ float xs[2][D], hs[2][D], ts[2][D], prt[2][2][D];
  __shared__ float redg[2][4][2];
  int t = threadIdx.x; int c = t & 255; int h = t >> 8;
  int f0 = blockIdx.x * 2;
  xs[h][c] = nt_emb[(size_t)(f0 + h) * D + c];
  __syncthreads();
  int d0 = h * 128;
  float a0 = 0.f, a1 = 0.f;
#pragma unroll 8
  for (int dd = 0; dd < 128; dd++) {
    float wv = W1[(size_t)(d0 + dd) * D + c];
    a0 += xs[0][d0 + dd] * wv; a1 += xs[1][d0 + dd] * wv;
  }
  prt[0][h][c] = a0; prt[1][h][c] = a1;
  __syncthreads();
  if (h == 0) {
    float bv = b1[c];
    hs[0][c] = prt[0][0][c] + prt[0][1][c] + bv;
    hs[1][c] = prt[1][0][c] + prt[1][1][c] + bv;
  }
  __syncthreads();
  for (int il = 0; il < 2; il++) {
    const float* W = resW + (size_t)(il * 2) * D * D;
    a0 = 0.f; a1 = 0.f;
#pragma unroll 8
    for (int dd = 0; dd < 128; dd++) {
      float wv = W[(size_t)(d0 + dd) * D + c];
      a0 += hs[0][d0 + dd] * wv; a1 += hs[1][d0 + dd] * wv;
    }
    prt[0][h][c] = a0; prt[1][h][c] = a1;
    __syncthreads();
    if (h == 0) {
      float bv = resb[(il * 2) * D + c];
      ts[0][c] = fmaxf(prt[0][0][c] + prt[0][1][c] + bv, 0.f);
      ts[1][c] = fmaxf(prt[1][0][c] + prt[1][1][c] + bv, 0.f);
    }
    __syncthreads();
    const float* W2 = resW + (size_t)(il * 2 + 1) * D * D;
    a0 = 0.f; a1 = 0.f;
#pragma unroll 8
    for (int dd = 0; dd < 128; dd++) {
      float wv = W2[(size_t)(d0 + dd) * D + c];
      a0 += ts[0][d0 + dd] * wv; a1 += ts[1][d0 + dd] * wv;
    }
    prt[0][h][c] = a0; prt[1][h][c] = a1;
    __syncthreads();
    if (h == 0) {
      float bv = resb[(il * 2 + 1) * D + c];
      hs[0][c] = fmaxf(prt[0][0][c] + prt[0][1][c] + bv, 0.f) + hs[0][c];
      hs[1][c] = fmaxf(prt[1][0][c] + prt[1][1][c] + bv, 0.f) + hs[1][c];
    }
    __syncthreads();
  }
  float y0 = hs[h][c] * Wo[c * 2 + 0], y1 = hs[h][c] * Wo[c * 2 + 1];
  for (int off = 32; off; off >>= 1) { y0 += __shfl_down(y0, off, 64); y1 += __shfl_down(y1, off, 64); }
  int wq = (t >> 6) & 3;
  if ((t & 63) == 0) { redg[h][wq][0] = y0; redg[h][wq][1] = y1; }
  __syncthreads();
  if (c == 0) {
    float s0 = redg[h][0][0] + redg[h][1][0] + redg[h][2][0] + redg[h][3][0] + bo[0];
    float s1 = redg[h][0][1] + redg[h][1][1] + redg[h][2][1] + redg[h][3][1] + bo[1];
    float m = fmaxf(s0, s1);
    float z = m + __logf(__expf(s0 - m) + __expf(s1 - m));
    split_scores[(f0 + h) * 2 + 0] = s0 - z;
    split_scores[(f0 + h) * 2 + 1] = s1 - z;
  }
}

// ---------------- rules: pack (egL, egR, rf, lf) per (r,a) as float4 ----------------
__global__ void k_glgr(const float* __restrict__ rule_W, const float* __restrict__ rule_b,
                       const float* __restrict__ split_scores,
                       const int* __restrict__ lf, const int* __restrict__ rf,
                       float4* __restrict__ rules) {
  __shared__ float red[128];
  __shared__ float shv[96];
  int r = blockIdx.x;
  int t = threadIdx.x;
  float x = (t < 96) ? (rule_W[t * CR + r] + rule_b[t]) : -INFINITY;
  red[t] = x; __syncthreads();
  for (int off = 64; off; off >>= 1) { if (t < off) red[t] = fmaxf(red[t], red[t + off]); __syncthreads(); }
  float m = red[0]; __syncthreads();
  red[t] = (t < 96) ? __expf(x - m) : 0.f; __syncthreads();
  for (int off = 64; off; off >>= 1) { if (t < off) red[t] += red[t + off]; __syncthreads(); }
  float z = m + __logf(red[0]);
  float s0 = split_scores[r * 2 + 0];
  if (t < 96) shv[t] = __expf((x - z) + s0);
  __syncthreads();
  if (t < CA) {
    float4 pk;
    pk.x = shv[t];
    pk.y = shv[CA + t];
    pk.z = __int_as_float(rf[r * CA + t]);
    pk.w = __int_as_float(lf[r * CA + t]);
    rules[r * CA + t] = pk;
  }
}

// ---------------- emission partition: 128 threads, 512-col tiles, RT=8 rows ----------------
#define RT 8
__global__ __launch_bounds__(128) void k_emit_partial(const float* __restrict__ nt_emb,
                               const float* __restrict__ emit_W,
                               const float* __restrict__ emit_b, float* __restrict__ partial) {
  __shared__ float xs[RT][D];
  __shared__ float ldsw[RT][2];
  int t = threadIdx.x;
  int f0 = blockIdx.x * RT;
  int v0 = blockIdx.y * 512 + t * 4;
  for (int idx = t; idx < RT * D; idx += 128) {
    int ri = idx >> 8, d = idx & 255;
    xs[ri][d] = nt_emb[(size_t)(f0 + ri) * D + d];
  }
  __syncthreads();
  float psum[RT];
  for (int ri = 0; ri < RT; ri++) psum[ri] = 0.f;
  if (v0 < V) {
    float acc[RT][4];
#pragma unroll
    for (int ri = 0; ri < RT; ri++)
      for (int j = 0; j < 4; j++) acc[ri][j] = 0.f;
    for (int d4 = 0; d4 < D / 4; d4++) {
      float4 w0 = *(const float4*)(emit_W + (size_t)(4 * d4 + 0) * V + v0);
      float4 w1 = *(const float4*)(emit_W + (size_t)(4 * d4 + 1) * V + v0);
      float4 w2 = *(const float4*)(emit_W + (size_t)(4 * d4 + 2) * V + v0);
      float4 w3 = *(const float4*)(emit_W + (size_t)(4 * d4 + 3) * V + v0);
#pragma unroll
      for (int ri = 0; ri < RT; ri++) {
        float4 xv = *(const float4*)(&xs[ri][4 * d4]);
        acc[ri][0] += xv.x * w0.x + xv.y * w1.x + xv.z * w2.x + xv.w * w3.x;
        acc[ri][1] += xv.x * w0.y + xv.y * w1.y + xv.z * w2.y + xv.w * w3.y;
        acc[ri][2] += xv.x * w0.z + xv.y * w1.z + xv.z * w2.z + xv.w * w3.z;
        acc[ri][3] += xv.x * w0.w + xv.y * w1.w + xv.z * w2.w + xv.w * w3.w;
      }
    }
    float4 eb = *(const float4*)(emit_b + v0);
#pragma unroll
    for (int ri = 0; ri < RT; ri++)
      psum[ri] = __expf(acc[ri][0] + eb.x) + __expf(acc[ri][1] + eb.y) +
                 __expf(acc[ri][2] + eb.z) + __expf(acc[ri][3] + eb.w);
  }
  int lane = t & 63, wid = t >> 6;
  for (int ri = 0; ri < RT; ri++) {
    float v = psum[ri];
    for (int off = 32; off; off >>= 1) v += __shfl_down(v, off, 64);
    if (lane == 0) ldsw[ri][wid] = v;
  }
  __syncthreads();
  if (t < RT) partial[(f0 + t) * 32 + blockIdx.y] = ldsw[t][0] + ldsw[t][1];
}

__global__ void k_logz(const float* __restrict__ partial, float* __restrict__ logZ) {
  int t = blockIdx.x * blockDim.x + threadIdx.x;
  if (t < CF) {
    float s = 0.f;
    for (int ct = 0; ct < 20; ct++) s += partial[t * 32 + ct];
    logZ[t] = __logf(s);
  }
}

// ---------------- terminal: ET[n][f][b] = exp(term - bmax), bmax to table ----------------
__global__ __launch_bounds__(512) void k_term(const float* __restrict__ nt_emb,
                       const float* __restrict__ emit_W,
                       const float* __restrict__ emit_b, const int* __restrict__ words,
                       const float* __restrict__ split_scores, const float* __restrict__ logZ,
                       float* __restrict__ ET, float* __restrict__ bmax) {
  __shared__ float vals[CF];
  __shared__ float redw[8];
  __shared__ float mfin;
  int blk = blockIdx.x;
  int b = blk / NN, n = blk % NN;
  int t = threadIdx.x;
  int lane = t & 63, wid = t >> 6;
  int wd = words[b * NN + n];
  float wc0 = emit_W[(size_t)(4 * lane + 0) * V + wd];
  float wc1 = emit_W[(size_t)(4 * lane + 1) * V + wd];
  float wc2 = emit_W[(size_t)(4 * lane + 2) * V + wd];
  float wc3 = emit_W[(size_t)(4 * lane + 3) * V + wd];
  float eb = emit_b[wd];
  float vmax = -INFINITY;
  int fbase = wid * 50;
  for (int k = 0; k < 50; k += 2) {
    int f0 = fbase + k, f1 = f0 + 1;
    float4 xa = *(const float4*)(nt_emb + (size_t)f0 * D + 4 * lane);
    float4 xb = *(const float4*)(nt_emb + (size_t)f1 * D + 4 * lane);
    float va = xa.x * wc0 + xa.y * wc1 + xa.z * wc2 + xa.w * wc3;
    float vb = xb.x * wc0 + xb.y * wc1 + xb.z * wc2 + xb.w * wc3;
    for (int off = 32; off; off >>= 1) {
      va += __shfl_down(va, off, 64);
      vb += __shfl_down(vb, off, 64);
    }
    if (lane == 0) {
      float fa = split_scores[f0 * 2 + 1] + (va + eb) - logZ[f0];
      float fb = split_scores[f1 * 2 + 1] + (vb + eb) - logZ[f1];
      vals[f0] = fa; vals[f1] = fb;
      vmax = fmaxf(vmax, fmaxf(fa, fb));
    }
  }
  if (lane == 0) redw[wid] = vmax;
  __syncthreads();
  if (t == 0) {
    float m = redw[0];
    for (int i2 = 1; i2 < 8; i2++) m = fmaxf(m, redw[i2]);
    mfin = m;
    bmax[(n * NN + n) * BB + b] = m;
  }
  __syncthreads();
  float m = mfin;
  for (int f = t; f < CF; f += 512) ET[((size_t)n * CF + f) * BB + b] = __expf(vals[f] - m);
}

// ---------------- CKY partial: block = (s, k, r-chunk), all 16 b, float4 over b ----------------
__global__ __launch_bounds__(512) void k_cky_part(const float4* __restrict__ rules,
                      const float* __restrict__ ET, const float* __restrict__ EB,
                      const float* __restrict__ bmax, float* __restrict__ partial,
                      int w, int rsplit) {
  __shared__ float SL[CF * PADF];
  __shared__ float SR[CF * PADF];
  __shared__ float sMbuf[21 * BB];
  __shared__ float cks[BB];
  __shared__ float4 sred[512];
  int t = threadIdx.x;
  int blk = blockIdx.x;
  int rb = blk % rsplit; int rem = blk / rsplit;
  int wm1 = w - 1;
  int k = rem % wm1; int s = rem / wm1;
  int i = s, j = s + w - 1;
  bool ld = (k == 0), rd = (k == wm1 - 1);
  if (t < BB * wm1) {
    int k2 = t >> 4, b2 = t & 15;
    sMbuf[t] = bmax[(i * NN + (i + k2)) * BB + b2] + bmax[((i + k2 + 1) * NN + j) * BB + b2];
  }
  __syncthreads();
  if (t < BB) {
    float M = sMbuf[t];
    for (int k2 = 1; k2 < wm1; k2++) M = fmaxf(M, sMbuf[k2 * BB + t]);
    cks[t] = __expf(sMbuf[k * BB + t] - M);
  }
  const float* srcL = ld ? (ET + (size_t)i * CF * BB) : (EB + (size_t)(i * NN + (i + k)) * CRP * BB);
  const float* srcR = rd ? (ET + (size_t)j * CF * BB) : (EB + (size_t)((i + k + 1) * NN + j) * CRP * BB);
  int rowsL = ld ? CF : CRP, rowsR = rd ? CF : CRP;
  for (int idx = t; idx < rowsL * 4; idx += 512) {
    int f = idx >> 2, q = idx & 3;
    *(float4*)&SL[f * PADF + q * 4] = *(const float4*)&srcL[f * BB + q * 4];
  }
  for (int idx = t; idx < rowsR * 4; idx += 512) {
    int f = idx >> 2, q = idx & 3;
    *(float4*)&SR[f * PADF + q * 4] = *(const float4*)&srcR[f * BB + q * 4];
  }
  __syncthreads();
  int nr = CR / rsplit;        // 120, 60, 30
  int asplit = 128 / nr;       // 1, 2, 4
  int bq = t & 3, rr = t >> 2; // rr < 128
  float4 acc = {0.f, 0.f, 0.f, 0.f};
  bool act = (rr < nr * asplit);
  int rloc = rr % nr, asub = rr / nr;
  int r = rb * nr + rloc;
  if (act) {
    int na = CA / asplit;
    const float4* rp = rules + (size_t)r * CA + asub * na;
    int boff = bq * 4;
    int aB = asub * na;
#pragma unroll 4
    for (int a0 = 0; a0 < na; a0++) {
      float4 rule = rp[a0];
      int a = aB + a0;
      int fL = __float_as_int(rule.z);
      int fR = __float_as_int(rule.w);
      int fLc = rd ? fL : min(fL, 120);
      int fRc = ld ? fR : min(fR, 120);
      float4 La = *(const float4*)&SL[a * PADF + boff];
      float4 Ra = *(const float4*)&SR[a * PADF + boff];
      float4 Rg = *(const float4*)&SR[fLc * PADF + boff];
      float4 Lg = *(const float4*)&SL[fRc * PADF + boff];
      acc.x += rule.x * (La.x * Rg.x) + rule.y * (Lg.x * Ra.x);
      acc.y += rule.x * (La.y * Rg.y) + rule.y * (Lg.y * Ra.y);
      acc.z += rule.x * (La.z * Rg.z) + rule.y * (Lg.z * Ra.z);
      acc.w += rule.x * (La.w * Rg.w) + rule.y * (Lg.w * Ra.w);
    }
  }
  if (asplit > 1) {
    sred[t] = acc;
    __syncthreads();
    if (act && asub == 0) {
      for (int s2 = 1; s2 < asplit; s2++) {
        float4 o = sred[t + s2 * nr * 4];
        acc.x += o.x; acc.y += o.y; acc.z += o.z; acc.w += o.w;
      }
    }
  }
  if (act && asub == 0) {
    float4 c4 = *(const float4*)&cks[bq * 4];
    acc.x *= c4.x; acc.y *= c4.y; acc.z *= c4.z; acc.w *= c4.w;
    *(float4*)&partial[(((size_t)s * 21 + k) * CR + r) * BB + bq * 4] = acc;
  }
}

// ---------------- CKY combine: sum k-partials, renormalize to EB + bmax ----------------
__global__ __launch_bounds__(512) void k_cky_comb(const float* __restrict__ partial,
                      float* __restrict__ EB, float* __restrict__ bmax, int w) {
  __shared__ float sums[CR * BB];
  __shared__ float sMbuf[21 * BB];
  __shared__ float msum[BB];
  __shared__ float Mb[BB];
  int t = threadIdx.x;
  int s = blockIdx.x;
  int i = s, j = s + w - 1;
  int wm1 = w - 1;
  if (t < BB * wm1) {
    int k2 = t >> 4, b2 = t & 15;
    sMbuf[t] = bmax[(i * NN + (i + k2)) * BB + b2] + bmax[((i + k2 + 1) * NN + j) * BB + b2];
  }
  __syncthreads();
  if (t < BB) {
    float M = sMbuf[t];
    for (int k2 = 1; k2 < wm1; k2++) M = fmaxf(M, sMbuf[k2 * BB + t]);
    Mb[t] = M;
  }
  int bq = t & 3, rr = t >> 2;
  float4 sum = {0.f, 0.f, 0.f, 0.f};
  if (rr < CR) {
    for (int k2 = 0; k2 < wm1; k2++) {
      float4 p = *(const float4*)&partial[(((size_t)s * 21 + k2) * CR + rr) * BB + bq * 4];
      sum.x += p.x; sum.y += p.y; sum.z += p.z; sum.w += p.w;
    }
    *(float4*)&sums[rr * BB + bq * 4] = sum;
  }
  __syncthreads();
  if (t < BB) {
    float m = 0.f;
    for (int r2 = 0; r2 < CR; r2++) m = fmaxf(m, sums[r2 * BB + t]);
    m = fmaxf(m, 1e-35f);
    msum[t] = m;
    bmax[(i * NN + j) * BB + t] = Mb[t] + __logf(m);
  }
  __syncthreads();
  if (rr < CR) {
    float4 m4 = *(const float4*)&msum[bq * 4];
    sum.x /= m4.x; sum.y /= m4.y; sum.z /= m4.z; sum.w /= m4.w;
    *(float4*)&EB[(((size_t)i * NN + j) * CRP + rr) * BB + bq * 4] = sum;
  }
  if (t < BB) EB[(((size_t)i * NN + j) * CRP + 120) * BB + t] = 0.f;
}

// ---------------- final: out[b] = -(bmax + log sum_r exp(root[r]) * EB[0][N-1][r][b]) ----------------
__global__ void k_final(const float* __restrict__ root_scores, const float* __restrict__ EB,
                        const float* __restrict__ bmax, float* __restrict__ out) {
  __shared__ float red[128];
  int b = blockIdx.x;
  int t = threadIdx.x;
  float x = (t < CR) ? __expf(root_scores[t]) * EB[(((size_t)0 * NN + (NN - 1)) * CRP + t) * BB + b] : 0.f;
  red[t] = x; __syncthreads();
  for (int off = 64; off; off >>= 1) { if (t < off) red[t] += red[t + off]; __syncthreads(); }
  if (t == 0) out[b] = -(bmax[(0 * NN + (NN - 1)) * BB + b] + __logf(red[0]));
}

extern "C" void kernel_launch(void* const* d_in, const int* in_sizes, int n_in,
                              void* d_out, int out_size, void* d_ws, size_t ws_size,
                              hipStream_t stream) {
  const float* nt_emb   = (const float*)d_in[1];
  const float* rule_W   = (const float*)d_in[2];
  const float* rule_b   = (const float*)d_in[3];
  const float* root_w   = (const float*)d_in[4];
  const float* root_b   = (const float*)d_in[5];
  const float* root_mask= (const float*)d_in[6];
  const float* split_W1 = (const float*)d_in[7];
  const float* split_b1 = (const float*)d_in[8];
  const float* res_W    = (const float*)d_in[9];
  const float* res_b    = (const float*)d_in[10];
  const float* split_Wo = (const float*)d_in[11];
  const float* split_bo = (const float*)d_in[12];
  const float* emit_W   = (const float*)d_in[13];
  const float* emit_b   = (const float*)d_in[14];
  const int*   words    = (const int*)d_in[15];
  const int*   lfunc    = (const int*)d_in[16];
  const int*   rfunc    = (const int*)d_in[17];

  float* ws = (float*)d_ws;
  float* ET           = ws;                          // 22*400*16   = 140800
  float* EB           = ET + NN * CF * BB;           // 22*22*121*16 = 937024
  float* bmaxbuf      = EB + NN * NN * CRP * BB;     // 7744
  float* partialK     = bmaxbuf + NN * NN * BB;      // 21*21*120*16 = 846720
  float* rules        = partialK + 21 * 21 * CR * BB;// 5760*4 = 23040
  float* root_scores  = rules + CR * CA * 4;         // 400
  float* split_scores = root_scores + CF;            // 800
  float* logZ         = split_scores + 2 * CF;       // 400
  float* partialE     = logZ + CF;                   // 400*32 = 12800

  hipLaunchKernelGGL(k_root, dim3(1), dim3(512), 0, stream, root_w, root_b, root_mask, root_scores);
  hipLaunchKernelGGL(k_mlp, dim3(CF / 2), dim3(512), 0, stream, nt_emb, split_W1, split_b1,
                     res_W, res_b, split_Wo, split_bo, split_scores);
  hipLaunchKernelGGL(k_glgr, dim3(CR), dim3(128), 0, stream, rule_W, rule_b, split_scores,
                     lfunc, rfunc, (float4*)rules);
  hipLaunchKernelGGL(k_emit_partial, dim3(CF / RT, 20), dim3(128), 0, stream, nt_emb, emit_W, emit_b, partialE);
  hipLaunchKernelGGL(k_logz, dim3(2), dim3(256), 0, stream, partialE, logZ);
  hipLaunchKernelGGL(k_term, dim3(BB * NN), dim3(512), 0, stream, nt_emb, emit_W, emit_b,
                     words, split_scores, logZ, ET, bmaxbuf);
  for (int w = 2; w <= NN; w++) {
    int S = NN - w + 1;
    int units = S * (w - 1);
    int rsplit = (units >= 224) ? 1 : ((units >= 112) ? 2 : 4);
    hipLaunchKernelGGL(k_cky_part, dim3(units * rsplit), dim3(512), 0, stream,
                       (const float4*)rules, ET, EB, bmaxbuf, partialK, w, rsplit);
    hipLaunchKernelGGL(k_cky_comb, dim3(S), dim3(512), 0, stream, partialK, EB, bmaxbuf, w);
  }
  hipLaunchKernelGGL(k_final, dim3(BB), dim3(128), 0, stream, root_scores, EB, bmaxbuf, (float*)d_out);
}